// Round 1
// baseline (535.154 us; speedup 1.0000x reference)
//
#include <hip/hip_runtime.h>
#include <hip/hip_bf16.h>
#include <stdint.h>

#define BATCH  8192
#define NFEAT  8192
#define DMODEL 1024

typedef unsigned short u16;
typedef __attribute__((ext_vector_type(8))) short  short8;
typedef __attribute__((ext_vector_type(4))) float  f32x4;

// fp32 -> bf16 round-to-nearest-even (inputs are finite; no NaN handling needed)
__device__ __forceinline__ u16 f2b(float f) {
    uint32_t u = __float_as_uint(f);
    u += 0x7fffu + ((u >> 16) & 1u);
    return (u16)(u >> 16);
}

// async global->LDS, 16B per lane; LDS dest is wave-uniform base + lane*16 (HW rule)
__device__ __forceinline__ void gld16(const u16* g, void* l) {
    __builtin_amdgcn_global_load_lds(
        (const __attribute__((address_space(1))) void*)(uintptr_t)g,
        (__attribute__((address_space(3))) void*)(uint32_t)(uintptr_t)l,
        16, 0, 0);
}

// ---------------- conversion kernels ----------------

// x [8192*8192] fp32 -> bf16, 8 elems/thread
__global__ void cvt_x_kernel(const float* __restrict__ x, u16* __restrict__ xb) {
    int i = blockIdx.x * blockDim.x + threadIdx.x;   // one per 8 elements
    const float4* xv = (const float4*)x;
    float4 a = xv[2 * i];
    float4 b = xv[2 * i + 1];
    union { u16 u[8]; uint4 v; } o;
    o.u[0] = f2b(a.x); o.u[1] = f2b(a.y); o.u[2] = f2b(a.z); o.u[3] = f2b(a.w);
    o.u[4] = f2b(b.x); o.u[5] = f2b(b.y); o.u[6] = f2b(b.z); o.u[7] = f2b(b.w);
    ((uint4*)xb)[i] = o.v;
}

// W [NFEAT][DMODEL] fp32 -> wb bf16 same layout, wt bf16 transposed [DMODEL][NFEAT]
__global__ void cvt_w_kernel(const float* __restrict__ W,
                             u16* __restrict__ wb, u16* __restrict__ wt) {
    __shared__ u16 tile[64][65];    // +1 pad breaks bank conflicts on transpose read
    const int f0 = blockIdx.x * 64;   // feature block
    const int d0 = blockIdx.y * 64;   // d_model block
    const int t  = threadIdx.x;       // 256 threads
#pragma unroll
    for (int rep = 0; rep < 16; ++rep) {
        int idx = rep * 256 + t;          // 0..4095
        int r = idx >> 6, c = idx & 63;
        float v = W[(size_t)(f0 + r) * DMODEL + d0 + c];
        u16 u = f2b(v);
        tile[r][c] = u;
        wb[(size_t)(f0 + r) * DMODEL + d0 + c] = u;
    }
    __syncthreads();
#pragma unroll
    for (int rep = 0; rep < 16; ++rep) {
        int idx = rep * 256 + t;
        int r = idx >> 6, c = idx & 63;   // r: d-row of wt, c: feature col
        wt[(size_t)(d0 + r) * NFEAT + f0 + c] = tile[c][r];
    }
}

// ---------------- GEMM: C = A @ B^T  (A [M][K], B [N][K], both bf16 row-major) ----------------
// m97 structure: 128x128 tile, BK=64, 4 waves (2x2), 16x16x32 bf16 MFMA, acc 4x4/wave,
// global_load_lds width-16 staging, single-buffered LDS with 2 barriers per K-step.
// EPI==0: store bf16 (h);  EPI==1: store fp32 relu(acc + bias[col]) (out)
template <int EPI>
__global__ __launch_bounds__(256)
void gemm_bt(const u16* __restrict__ A, const u16* __restrict__ B,
             void* __restrict__ Cout, const float* __restrict__ bias,
             int M, int N, int K) {
    __shared__ __align__(16) u16 As[128 * 64];
    __shared__ __align__(16) u16 Bs[128 * 64];

    const int tid  = threadIdx.x;
    const int lane = tid & 63;
    const int wave = tid >> 6;
    const int wm0  = (wave >> 1) * 64;   // wave row offset in tile
    const int wn0  = (wave & 1) * 64;    // wave col offset in tile
    const int l15  = lane & 15;
    const int lhi  = lane >> 4;

    const int tm0 = blockIdx.y * 128;
    const int tn0 = blockIdx.x * 128;

    // staging geometry: 16 chunks of 1024B per tile; wave stages chunks wave*4 .. wave*4+3
    // LDS linear [128][64] bf16 row-major; lane covers (row = chunk*8 + lane/8, col = (lane&7)*8)
    const int srow = wave * 32 + (lane >> 3);
    const int scol = (lane & 7) * 8;
    const size_t a_base = (size_t)(tm0 + srow) * K + scol;
    const size_t b_base = (size_t)(tn0 + srow) * K + scol;

    f32x4 acc[4][4] = {};

    const u16* Ab = As + (wm0 + l15) * 64 + lhi * 8;
    const u16* Bb = Bs + (wn0 + l15) * 64 + lhi * 8;

    for (int k0 = 0; k0 < K; k0 += 64) {
#pragma unroll
        for (int c = 0; c < 4; ++c) {
            gld16(A + a_base + (size_t)(8 * c) * K + k0, (char*)As + (wave * 4 + c) * 1024);
            gld16(B + b_base + (size_t)(8 * c) * K + k0, (char*)Bs + (wave * 4 + c) * 1024);
        }
        __syncthreads();   // compiler emits vmcnt(0) drain before barrier
#pragma unroll
        for (int kk = 0; kk < 64; kk += 32) {
            short8 a[4], b[4];
#pragma unroll
            for (int m = 0; m < 4; ++m) a[m] = *(const short8*)(Ab + m * 16 * 64 + kk);
#pragma unroll
            for (int n = 0; n < 4; ++n) b[n] = *(const short8*)(Bb + n * 16 * 64 + kk);
#pragma unroll
            for (int m = 0; m < 4; ++m)
#pragma unroll
                for (int n = 0; n < 4; ++n)
                    acc[m][n] = __builtin_amdgcn_mfma_f32_16x16x32_bf16(a[m], b[n], acc[m][n], 0, 0, 0);
        }
        __syncthreads();
    }

    // epilogue: C/D mapping col = lane&15, row = 4*(lane>>4) + reg
    if (EPI == 0) {
        u16* H = (u16*)Cout;
#pragma unroll
        for (int m = 0; m < 4; ++m) {
#pragma unroll
            for (int n = 0; n < 4; ++n) {
                const int col  = tn0 + wn0 + n * 16 + l15;
                const int row0 = tm0 + wm0 + m * 16 + lhi * 4;
#pragma unroll
                for (int r = 0; r < 4; ++r)
                    H[(size_t)(row0 + r) * N + col] = f2b(acc[m][n][r]);
            }
        }
    } else {
        float* O = (float*)Cout;
#pragma unroll
        for (int n = 0; n < 4; ++n) {
            const int col = tn0 + wn0 + n * 16 + l15;
            const float bv = bias[col];
#pragma unroll
            for (int m = 0; m < 4; ++m) {
                const int row0 = tm0 + wm0 + m * 16 + lhi * 4;
#pragma unroll
                for (int r = 0; r < 4; ++r) {
                    float v = acc[m][n][r] + bv;
                    O[(size_t)(row0 + r) * N + col] = v > 0.f ? v : 0.f;
                }
            }
        }
    }
}

// ---------------- launch ----------------

extern "C" void kernel_launch(void* const* d_in, const int* in_sizes, int n_in,
                              void* d_out, int out_size, void* d_ws, size_t ws_size,
                              hipStream_t stream) {
    const float* x    = (const float*)d_in[0];   // [8192, 8192]
    const float* W    = (const float*)d_in[1];   // [8192, 1024]
    const float* bias = (const float*)d_in[2];   // [8192]
    float* out = (float*)d_out;                  // [8192, 8192] fp32

    // workspace layout (176 MB total)
    char* ws = (char*)d_ws;
    u16* xb = (u16*)ws;                                        // 8192*8192*2 = 134217728
    u16* wt = (u16*)(ws + 134217728);                          // [1024][8192]  16777216
    u16* wb = (u16*)(ws + 134217728 + 16777216);               // [8192][1024]  16777216
    u16* hb = (u16*)(ws + 134217728 + 2 * 16777216);           // [8192][1024]  16777216

    // 1) convert x to bf16
    cvt_x_kernel<<<(BATCH * NFEAT / 8) / 256, 256, 0, stream>>>(x, xb);

    // 2) convert W to bf16 (both layouts)
    cvt_w_kernel<<<dim3(NFEAT / 64, DMODEL / 64), 256, 0, stream>>>(W, wb, wt);

    // 3) h = x @ W  -> bf16   (A=xb [8192][8192], B^T=wt [1024][8192])
    gemm_bt<0><<<dim3(DMODEL / 128, BATCH / 128), 256, 0, stream>>>(
        xb, wt, hb, nullptr, BATCH, DMODEL, NFEAT);

    // 4) out = relu(h @ W^T + bias)  (A=hb [8192][1024], B^T=wb [8192][1024])
    gemm_bt<1><<<dim3(NFEAT / 128, BATCH / 128), 256, 0, stream>>>(
        hb, wb, out, bias, BATCH, NFEAT, DMODEL);
}

// Round 2
// 469.998 us; speedup vs baseline: 1.1386x; 1.1386x over previous
//
#include <hip/hip_runtime.h>
#include <hip/hip_bf16.h>
#include <stdint.h>

#define BATCH  8192
#define NFEAT  8192
#define DMODEL 1024

typedef unsigned short u16;
typedef __attribute__((ext_vector_type(8))) short  short8;
typedef __attribute__((ext_vector_type(4))) float  f32x4;

// fp32 -> bf16 round-to-nearest-even (inputs are finite; no NaN handling needed)
__device__ __forceinline__ u16 f2b(float f) {
    uint32_t u = __float_as_uint(f);
    u += 0x7fffu + ((u >> 16) & 1u);
    return (u16)(u >> 16);
}

// async global->LDS, 16B per lane; LDS dest is wave-uniform base + lane*16 (HW rule)
__device__ __forceinline__ void gld16(const u16* g, void* l) {
    __builtin_amdgcn_global_load_lds(
        (const __attribute__((address_space(1))) void*)(uintptr_t)g,
        (__attribute__((address_space(3))) void*)(uint32_t)(uintptr_t)l,
        16, 0, 0);
}

// ---------------- conversion kernels ----------------

__global__ void cvt_x_kernel(const float* __restrict__ x, u16* __restrict__ xb) {
    int i = blockIdx.x * blockDim.x + threadIdx.x;   // one per 8 elements
    const float4* xv = (const float4*)x;
    float4 a = xv[2 * i];
    float4 b = xv[2 * i + 1];
    union { u16 u[8]; uint4 v; } o;
    o.u[0] = f2b(a.x); o.u[1] = f2b(a.y); o.u[2] = f2b(a.z); o.u[3] = f2b(a.w);
    o.u[4] = f2b(b.x); o.u[5] = f2b(b.y); o.u[6] = f2b(b.z); o.u[7] = f2b(b.w);
    ((uint4*)xb)[i] = o.v;
}

// W [NFEAT][DMODEL] fp32 -> wb bf16 same layout, wt bf16 transposed [DMODEL][NFEAT]
__global__ void cvt_w_kernel(const float* __restrict__ W,
                             u16* __restrict__ wb, u16* __restrict__ wt) {
    __shared__ u16 tile[64][65];
    const int f0 = blockIdx.x * 64;
    const int d0 = blockIdx.y * 64;
    const int t  = threadIdx.x;
#pragma unroll
    for (int rep = 0; rep < 16; ++rep) {
        int idx = rep * 256 + t;
        int r = idx >> 6, c = idx & 63;
        float v = W[(size_t)(f0 + r) * DMODEL + d0 + c];
        u16 u = f2b(v);
        tile[r][c] = u;
        wb[(size_t)(f0 + r) * DMODEL + d0 + c] = u;
    }
    __syncthreads();
#pragma unroll
    for (int rep = 0; rep < 16; ++rep) {
        int idx = rep * 256 + t;
        int r = idx >> 6, c = idx & 63;
        wt[(size_t)(d0 + r) * NFEAT + f0 + c] = tile[c][r];
    }
}

// ---------------- GEMM 1: m97 structure (128x128, BK=64, 4 waves) ----------------
// C = A @ B^T, A [M][K], B [N][K] bf16; stores bf16.
__global__ __launch_bounds__(256)
void gemm_bt_h(const u16* __restrict__ A, const u16* __restrict__ B,
               u16* __restrict__ H, int M, int N, int K) {
    __shared__ __align__(16) u16 As[128 * 64];
    __shared__ __align__(16) u16 Bs[128 * 64];

    const int tid  = threadIdx.x;
    const int lane = tid & 63;
    const int wave = tid >> 6;
    const int wm0  = (wave >> 1) * 64;
    const int wn0  = (wave & 1) * 64;
    const int l15  = lane & 15;
    const int lhi  = lane >> 4;

    const int tm0 = blockIdx.y * 128;
    const int tn0 = blockIdx.x * 128;

    const int srow = wave * 32 + (lane >> 3);
    const int scol = (lane & 7) * 8;
    const size_t a_base = (size_t)(tm0 + srow) * K + scol;
    const size_t b_base = (size_t)(tn0 + srow) * K + scol;

    f32x4 acc[4][4] = {};

    const u16* Ab = As + (wm0 + l15) * 64 + lhi * 8;
    const u16* Bb = Bs + (wn0 + l15) * 64 + lhi * 8;

    for (int k0 = 0; k0 < K; k0 += 64) {
#pragma unroll
        for (int c = 0; c < 4; ++c) {
            gld16(A + a_base + (size_t)(8 * c) * K + k0, (char*)As + (wave * 4 + c) * 1024);
            gld16(B + b_base + (size_t)(8 * c) * K + k0, (char*)Bs + (wave * 4 + c) * 1024);
        }
        __syncthreads();
#pragma unroll
        for (int kk = 0; kk < 64; kk += 32) {
            short8 a[4], b[4];
#pragma unroll
            for (int m = 0; m < 4; ++m) a[m] = *(const short8*)(Ab + m * 16 * 64 + kk);
#pragma unroll
            for (int n = 0; n < 4; ++n) b[n] = *(const short8*)(Bb + n * 16 * 64 + kk);
#pragma unroll
            for (int m = 0; m < 4; ++m)
#pragma unroll
                for (int n = 0; n < 4; ++n)
                    acc[m][n] = __builtin_amdgcn_mfma_f32_16x16x32_bf16(a[m], b[n], acc[m][n], 0, 0, 0);
        }
        __syncthreads();
    }

#pragma unroll
    for (int m = 0; m < 4; ++m)
#pragma unroll
        for (int n = 0; n < 4; ++n) {
            const int col  = tn0 + wn0 + n * 16 + l15;
            const int row0 = tm0 + wm0 + m * 16 + lhi * 4;
#pragma unroll
            for (int r = 0; r < 4; ++r)
                H[(size_t)(row0 + r) * N + col] = f2b(acc[m][n][r]);
        }
}

// ---------------- GEMM 2: 256x256 8-phase (T2 swizzle + T3/T4 counted vmcnt + T5) ----
// C = relu(A @ B^T + bias), A [M][K], B [N][K] bf16, out fp32.
// 512 threads = 8 waves (2M x 4N); BK=64; LDS 128 KiB (2 dbuf x {A,B} x 2 halves x 16 KiB).
// LDS layout per 16 KiB half-tile: 16 subtiles of 1024 B, subtile (sr,sc) = 16 rows x 32 cols,
// st_16x32 swizzle: phys col-chunk = logical chunk ^ ((row&8)>>3 <<1). Staged via pre-swizzled
// per-lane GLOBAL source addresses + linear global_load_lds dest (rule #21).
__global__ __launch_bounds__(512, 2)
void gemm2_8phase(const u16* __restrict__ A, const u16* __restrict__ B,
                  float* __restrict__ O, const float* __restrict__ bias,
                  int N, int K) {
    const int NT = K >> 6;                 // K-tiles
    __shared__ __align__(1024) char lds[131072];
    const int BOFF = 65536;

    const int tid  = threadIdx.x;
    const int lane = tid & 63;
    const int wave = tid >> 6;             // 0..7
    const int wm   = wave >> 2;            // 0..1  (row half)
    const int wn   = wave & 3;             // 0..3  (64-col group)

    // XCD-aware bijective swizzle (nwg % 8 == 0)
    const int nwg = gridDim.x;
    const int swz = (blockIdx.x & 7) * (nwg >> 3) + (blockIdx.x >> 3);
    const int ntn = N >> 8;
    const int tm0 = (swz / ntn) << 8;
    const int tn0 = (swz % ntn) << 8;

    // ---- staging geometry (per thread) ----
    // stage inst (wave w, j) covers subtile st = j*8 + w  ->  sr = (w>>1)+j*4, sc = w&1
    // lane l -> subtile row rs = l>>2, phys chunk pc = l&3; source logical chunk = pc ^ ((rs&8)>>3<<1)
    const int srl = lane >> 2;
    const int sch = (lane & 3) ^ (((lane >> 5) & 1) << 1);
    const int scol  = (wave & 1) * 32 + sch * 8;        // col within K-tile
    const int srow0 = (wave >> 1) * 16 + srl;           // row within half (j=0); j=1 adds 64

    const u16* pa[2][2];  // [half][j]
    const u16* pb[2][2];
    pa[0][0] = A + (size_t)(tm0 + srow0)       * K + scol;
    pa[0][1] = A + (size_t)(tm0 + srow0 + 64)  * K + scol;
    pa[1][0] = A + (size_t)(tm0 + 128 + srow0)      * K + scol;
    pa[1][1] = A + (size_t)(tm0 + 128 + srow0 + 64) * K + scol;
    pb[0][0] = B + (size_t)(tn0 + srow0)       * K + scol;
    pb[0][1] = B + (size_t)(tn0 + srow0 + 64)  * K + scol;
    pb[1][0] = B + (size_t)(tn0 + 128 + srow0)      * K + scol;
    pb[1][1] = B + (size_t)(tn0 + 128 + srow0 + 64) * K + scol;

    auto STAGE = [&](int tau, int isB, int half) {
        if (tau < NT) {
            char* d = lds + (isB ? BOFF : 0) + (tau & 1) * 32768 + half * 16384 + wave * 1024;
            const u16* p0 = (isB ? pb[half][0] : pa[half][0]) + (size_t)tau * 64;
            const u16* p1 = (isB ? pb[half][1] : pa[half][1]) + (size_t)tau * 64;
            gld16(p0, d);
            gld16(p1, d + 8192);
        }
    };

    // ---- fragment-read geometry ----
    const int l15 = lane & 15, lhi = lane >> 4;
    const int pch = lhi ^ (((lane >> 3) & 1) << 1);     // swizzled chunk on read side
    const int lof = l15 * 64 + pch * 16;                // byte offset within subtile grid

    short8 a[4][2];      // 4 m-frags (current mh) x 2 k-slices
    short8 b[4][2];      // all 4 n-frags x 2 k-slices (resident per K-tile)
    f32x4  acc[8][4] = {};

    const char* Ab;
    const char* Bb;
    auto LDA_ = [&](int mh) {
#pragma unroll
        for (int fm = 0; fm < 4; ++fm)
#pragma unroll
            for (int ks = 0; ks < 2; ++ks)
                a[fm][ks] = *(const short8*)(Ab + ((mh * 4 + fm) * 2 + ks) * 1024);
    };
    auto LDB_ = [&](int nh) {
#pragma unroll
        for (int fn = 0; fn < 2; ++fn)
#pragma unroll
            for (int ks = 0; ks < 2; ++ks)
                b[nh * 2 + fn][ks] = *(const short8*)(Bb + (((wn & 1) * 4 + nh * 2 + fn) * 2 + ks) * 1024);
    };
    auto MMA_ = [&](int mh, int nh) {
#pragma unroll
        for (int ks = 0; ks < 2; ++ks)
#pragma unroll
            for (int fm = 0; fm < 4; ++fm)
#pragma unroll
                for (int fn = 0; fn < 2; ++fn)
                    acc[mh * 4 + fm][nh * 2 + fn] = __builtin_amdgcn_mfma_f32_16x16x32_bf16(
                        a[fm][ks], b[nh * 2 + fn][ks], acc[mh * 4 + fm][nh * 2 + fn], 0, 0, 0);
    };

#define SYNC_IN()  do { __builtin_amdgcn_sched_barrier(0); __builtin_amdgcn_s_barrier(); \
                        asm volatile("s_waitcnt lgkmcnt(0)" ::: "memory");               \
                        __builtin_amdgcn_sched_barrier(0); } while (0)
#define SYNC_OUT() do { __builtin_amdgcn_s_setprio(0); __builtin_amdgcn_sched_barrier(0); \
                        __builtin_amdgcn_s_barrier(); } while (0)

    // ---- prologue: tile0 {A0,A1,B0,B1} + tile1 {B0,B1}  (12 loads/thread) ----
    STAGE(0, 0, 0); STAGE(0, 0, 1); STAGE(0, 1, 0); STAGE(0, 1, 1);
    STAGE(1, 1, 0); STAGE(1, 1, 1);
    asm volatile("s_waitcnt vmcnt(4)" ::: "memory");    // tile0 landed; tile1 B's in flight
    __builtin_amdgcn_s_barrier();

    for (int t = 0; t < NT; ++t) {
        Ab = lds + (t & 1) * 32768 + wm * 16384 + lof;
        Bb = lds + BOFF + (t & 1) * 32768 + (wn >> 1) * 16384 + lof;

        // q0: reads A[mh0](8) + B[nh0](4); stage (t+1, A half0)
        LDA_(0); LDB_(0);
        STAGE(t + 1, 0, 0);
        asm volatile("s_waitcnt lgkmcnt(8)" ::: "memory");
        SYNC_IN();
        __builtin_amdgcn_s_setprio(1);
        MMA_(0, 0);
        SYNC_OUT();

        // q1: reads B[nh1](4); stage (t+1, A half1)
        LDB_(1);
        STAGE(t + 1, 0, 1);
        SYNC_IN();
        __builtin_amdgcn_s_setprio(1);
        MMA_(0, 1);
        SYNC_OUT();

        // q2: reads A[mh1](8); stage (t+2, B half0)  [B-h0 last read q0 -> safe]
        LDA_(1);
        STAGE(t + 2, 1, 0);
        SYNC_IN();
        __builtin_amdgcn_s_setprio(1);
        MMA_(1, 1);
        SYNC_OUT();

        // q3: no reads; stage (t+2, B half1)  [B-h1 last read q1 -> safe]
        STAGE(t + 2, 1, 1);
        __builtin_amdgcn_sched_barrier(0);
        __builtin_amdgcn_s_barrier();
        asm volatile("s_waitcnt lgkmcnt(0)" ::: "memory");
        __builtin_amdgcn_sched_barrier(0);
        __builtin_amdgcn_s_setprio(1);
        MMA_(1, 0);
        __builtin_amdgcn_s_setprio(0);
        __builtin_amdgcn_sched_barrier(0);
        // counted drain: tile t+1 fully landed; (t+2) B's stay in flight
        if (t < NT - 2)       asm volatile("s_waitcnt vmcnt(4)" ::: "memory");
        else if (t == NT - 2) asm volatile("s_waitcnt vmcnt(0)" ::: "memory");
        __builtin_amdgcn_s_barrier();
    }

    // ---- epilogue: fp32 relu(acc + bias) ----
    const int orow = tm0 + wm * 128;
    const int ocol = tn0 + wn * 64;
    float bv[4];
#pragma unroll
    for (int fn = 0; fn < 4; ++fn) bv[fn] = bias[ocol + fn * 16 + l15];
#pragma unroll
    for (int fm = 0; fm < 8; ++fm) {
        const int row0 = orow + fm * 16 + lhi * 4;
#pragma unroll
        for (int fn = 0; fn < 4; ++fn) {
            const int col = ocol + fn * 16 + l15;
#pragma unroll
            for (int r = 0; r < 4; ++r) {
                float v = acc[fm][fn][r] + bv[fn];
                O[(size_t)(row0 + r) * N + col] = v > 0.f ? v : 0.f;
            }
        }
    }
#undef SYNC_IN
#undef SYNC_OUT
}

// ---------------- launch ----------------

extern "C" void kernel_launch(void* const* d_in, const int* in_sizes, int n_in,
                              void* d_out, int out_size, void* d_ws, size_t ws_size,
                              hipStream_t stream) {
    const float* x    = (const float*)d_in[0];   // [8192, 8192]
    const float* W    = (const float*)d_in[1];   // [8192, 1024]
    const float* bias = (const float*)d_in[2];   // [8192]
    float* out = (float*)d_out;                  // [8192, 8192] fp32

    char* ws = (char*)d_ws;
    u16* xb = (u16*)ws;                                        // 134217728 B
    u16* wt = (u16*)(ws + 134217728);                          // [1024][8192]
    u16* wb = (u16*)(ws + 134217728 + 16777216);               // [8192][1024]
    u16* hb = (u16*)(ws + 134217728 + 2 * 16777216);           // [8192][1024]

    cvt_x_kernel<<<(BATCH * NFEAT / 8) / 256, 256, 0, stream>>>(x, xb);
    cvt_w_kernel<<<dim3(NFEAT / 64, DMODEL / 64), 256, 0, stream>>>(W, wb, wt);

    // h = x @ W -> bf16 (m97 128^2; N=1024 too narrow for the 256^2 schedule)
    gemm_bt_h<<<dim3(DMODEL / 128, BATCH / 128), 256, 0, stream>>>(
        xb, wt, hb, BATCH, DMODEL, NFEAT);

    // out = relu(h @ W^T + bias)  (256^2 8-phase; grid 32x32 = 1024 blocks)
    gemm2_8phase<<<dim3((BATCH / 256) * (NFEAT / 256)), 512, 0, stream>>>(
        hb, wb, out, bias, NFEAT, DMODEL);
}

// Round 3
// 407.497 us; speedup vs baseline: 1.3133x; 1.1534x over previous
//
#include <hip/hip_runtime.h>
#include <hip/hip_bf16.h>
#include <stdint.h>

#define BATCH  8192
#define NFEAT  8192
#define DMODEL 1024

typedef unsigned short u16;
typedef __attribute__((ext_vector_type(8))) short  short8;
typedef __attribute__((ext_vector_type(4))) float  f32x4;

// fp32 -> bf16 round-to-nearest-even
__device__ __forceinline__ u16 f2b(float f) {
    uint32_t u = __float_as_uint(f);
    u += 0x7fffu + ((u >> 16) & 1u);
    return (u16)(u >> 16);
}

// async global->LDS, 16B per lane; LDS dest is wave-uniform base + lane*16 (HW rule)
__device__ __forceinline__ void gld16(const u16* g, void* l) {
    __builtin_amdgcn_global_load_lds(
        (const __attribute__((address_space(1))) void*)(uintptr_t)g,
        (__attribute__((address_space(3))) void*)(uint32_t)(uintptr_t)l,
        16, 0, 0);
}

// ---------------- conversion kernels ----------------

__global__ void cvt_x_kernel(const float* __restrict__ x, u16* __restrict__ xb) {
    int i = blockIdx.x * blockDim.x + threadIdx.x;
    const float4* xv = (const float4*)x;
    float4 a = xv[2 * i];
    float4 b = xv[2 * i + 1];
    union { u16 u[8]; uint4 v; } o;
    o.u[0] = f2b(a.x); o.u[1] = f2b(a.y); o.u[2] = f2b(a.z); o.u[3] = f2b(a.w);
    o.u[4] = f2b(b.x); o.u[5] = f2b(b.y); o.u[6] = f2b(b.z); o.u[7] = f2b(b.w);
    ((uint4*)xb)[i] = o.v;
}

__global__ void cvt_w_kernel(const float* __restrict__ W,
                             u16* __restrict__ wb, u16* __restrict__ wt) {
    __shared__ u16 tile[64][65];
    const int f0 = blockIdx.x * 64;
    const int d0 = blockIdx.y * 64;
    const int t  = threadIdx.x;
#pragma unroll
    for (int rep = 0; rep < 16; ++rep) {
        int idx = rep * 256 + t;
        int r = idx >> 6, c = idx & 63;
        float v = W[(size_t)(f0 + r) * DMODEL + d0 + c];
        u16 u = f2b(v);
        tile[r][c] = u;
        wb[(size_t)(f0 + r) * DMODEL + d0 + c] = u;
    }
    __syncthreads();
#pragma unroll
    for (int rep = 0; rep < 16; ++rep) {
        int idx = rep * 256 + t;
        int r = idx >> 6, c = idx & 63;
        wt[(size_t)(d0 + r) * NFEAT + f0 + c] = tile[c][r];
    }
}

#define SYNC_IN()  do { __builtin_amdgcn_sched_barrier(0); __builtin_amdgcn_s_barrier(); \
                        asm volatile("s_waitcnt lgkmcnt(0)" ::: "memory");               \
                        __builtin_amdgcn_sched_barrier(0); } while (0)
#define SYNC_OUT() do { __builtin_amdgcn_s_setprio(0); __builtin_amdgcn_sched_barrier(0); \
                        __builtin_amdgcn_s_barrier(); } while (0)

// ---------------- GEMM 1: 256x128 tile, 8-phase, 8 waves ----------------
// H = A @ B^T (bf16 out). A [M][K], B [N][K]. Grid = (M/256)*(N/128) = 256 blocks.
// LDS 96 KiB: A 2dbuf x 2halves x 16KiB @0, B 2dbuf x 16KiB @65536.
// st_16x32 swizzle via pre-swizzled global source + swizzled read (rule #21).
__global__ __launch_bounds__(512, 2)
void gemm1_8phase(const u16* __restrict__ A, const u16* __restrict__ B,
                  u16* __restrict__ H, int N, int K) {
    const int NT = K >> 6;
    __shared__ __align__(1024) char lds[98304];
    const int BOFF = 65536;

    const int tid  = threadIdx.x;
    const int lane = tid & 63;
    const int wave = tid >> 6;             // 0..7
    const int wm   = wave >> 2;            // 0..1 (128-row half)
    const int wn   = wave & 3;             // 0..3 (32-col group)

    const int nwg = gridDim.x;
    const int swz = (blockIdx.x & 7) * (nwg >> 3) + (blockIdx.x >> 3);
    const int ntn = N >> 7;                // n-blocks (8)
    const int tm0 = (swz / ntn) << 8;
    const int tn0 = (swz % ntn) << 7;

    // staging geometry (identical to verified gemm2 A-side)
    const int srl = lane >> 2;
    const int sch = (lane & 3) ^ (((lane >> 5) & 1) << 1);
    const int scol  = (wave & 1) * 32 + sch * 8;
    const int srow0 = (wave >> 1) * 16 + srl;

    const u16* pa[2][2];
    pa[0][0] = A + (size_t)(tm0 + srow0)            * K + scol;
    pa[0][1] = A + (size_t)(tm0 + srow0 + 64)       * K + scol;
    pa[1][0] = A + (size_t)(tm0 + 128 + srow0)      * K + scol;
    pa[1][1] = A + (size_t)(tm0 + 128 + srow0 + 64) * K + scol;
    const u16* pb[2];
    pb[0] = B + (size_t)(tn0 + srow0)      * K + scol;
    pb[1] = B + (size_t)(tn0 + srow0 + 64) * K + scol;

    auto STAGE_A = [&](int tau, int half) {
        if (tau < NT) {
            char* d = lds + (tau & 1) * 32768 + half * 16384 + wave * 1024;
            gld16(pa[half][0] + (size_t)tau * 64, d);
            gld16(pa[half][1] + (size_t)tau * 64, d + 8192);
        }
    };
    auto STAGE_B = [&](int tau) {
        if (tau < NT) {
            char* d = lds + BOFF + (tau & 1) * 16384 + wave * 1024;
            gld16(pb[0] + (size_t)tau * 64, d);
            gld16(pb[1] + (size_t)tau * 64, d + 8192);
        }
    };

    // fragment-read geometry
    const int l15 = lane & 15, lhi = lane >> 4;
    const int pch = lhi ^ (((lane >> 3) & 1) << 1);
    const int lof = l15 * 64 + pch * 16;

    short8 a[4][2];          // 4 m-frags of current mh x 2 k-slices
    short8 b[2][2];          // both n-frags x 2 k-slices (resident per K-tile)
    f32x4  acc[8][2] = {};

    const char* Ab;
    const char* Bb;
    auto LDA_ = [&](int mh) {
#pragma unroll
        for (int fm = 0; fm < 4; ++fm)
#pragma unroll
            for (int ks = 0; ks < 2; ++ks)
                a[fm][ks] = *(const short8*)(Ab + ((mh * 4 + fm) * 2 + ks) * 1024);
    };
    auto LDB_ = [&](int nh) {
#pragma unroll
        for (int ks = 0; ks < 2; ++ks)
            b[nh][ks] = *(const short8*)(Bb + (nh * 2 + ks) * 1024);
    };
    auto MMA_ = [&](int mh, int nh) {
#pragma unroll
        for (int ks = 0; ks < 2; ++ks)
#pragma unroll
            for (int fm = 0; fm < 4; ++fm)
                acc[mh * 4 + fm][nh] = __builtin_amdgcn_mfma_f32_16x16x32_bf16(
                    a[fm][ks], b[nh][ks], acc[mh * 4 + fm][nh], 0, 0, 0);
    };

    // prologue: A(0,h0) A(0,h1) B(0) B(1); wait first 6 of 8 loads
    STAGE_A(0, 0); STAGE_A(0, 1); STAGE_B(0); STAGE_B(1);
    asm volatile("s_waitcnt vmcnt(2)" ::: "memory");
    __builtin_amdgcn_s_barrier();

    for (int t = 0; t < NT; ++t) {
        Ab = lds + (t & 1) * 32768 + wm * 16384 + lof;
        Bb = lds + BOFF + (t & 1) * 16384 + wn * 4096 + lof;

        // q0: reads A[mh0](8) + B[nh0](2); stage A(t+1,h0)
        LDA_(0); LDB_(0);
        STAGE_A(t + 1, 0);
        SYNC_IN();
        __builtin_amdgcn_s_setprio(1);
        MMA_(0, 0);
        SYNC_OUT();

        // q1: reads B[nh1](2); stage A(t+1,h1)
        LDB_(1);
        STAGE_A(t + 1, 1);
        SYNC_IN();
        __builtin_amdgcn_s_setprio(1);
        MMA_(0, 1);
        SYNC_OUT();

        // q2: reads A[mh1](8); stage B(t+2)  [B buf t&1 last read q1 -> safe]
        LDA_(1);
        STAGE_B(t + 2);
        SYNC_IN();
        __builtin_amdgcn_s_setprio(1);
        MMA_(1, 1);
        SYNC_OUT();

        // q3: no reads
        __builtin_amdgcn_sched_barrier(0);
        __builtin_amdgcn_s_barrier();
        __builtin_amdgcn_s_setprio(1);
        MMA_(1, 0);
        __builtin_amdgcn_s_setprio(0);
        __builtin_amdgcn_sched_barrier(0);
        // in flight: B(t+1)2 A(t+1,h0)2 A(t+1,h1)2 B(t+2)2 -> keep only B(t+2)
        if (t < NT - 2)       asm volatile("s_waitcnt vmcnt(2)" ::: "memory");
        else if (t == NT - 2) asm volatile("s_waitcnt vmcnt(0)" ::: "memory");
        __builtin_amdgcn_s_barrier();
    }

    // epilogue: bf16 store
    const int orow = tm0 + wm * 128;
    const int ocol = tn0 + wn * 32;
#pragma unroll
    for (int fm = 0; fm < 8; ++fm) {
        const int row0 = orow + fm * 16 + lhi * 4;
#pragma unroll
        for (int nh = 0; nh < 2; ++nh) {
            const int col = ocol + nh * 16 + l15;
#pragma unroll
            for (int r = 0; r < 4; ++r)
                H[(size_t)(row0 + r) * N + col] = f2b(acc[fm][nh][r]);
        }
    }
}

// ---------------- GEMM 2: 256x256 8-phase (unchanged, verified) ----------------
__global__ __launch_bounds__(512, 2)
void gemm2_8phase(const u16* __restrict__ A, const u16* __restrict__ B,
                  float* __restrict__ O, const float* __restrict__ bias,
                  int N, int K) {
    const int NT = K >> 6;
    __shared__ __align__(1024) char lds[131072];
    const int BOFF = 65536;

    const int tid  = threadIdx.x;
    const int lane = tid & 63;
    const int wave = tid >> 6;
    const int wm   = wave >> 2;
    const int wn   = wave & 3;

    const int nwg = gridDim.x;
    const int swz = (blockIdx.x & 7) * (nwg >> 3) + (blockIdx.x >> 3);
    const int ntn = N >> 8;
    const int tm0 = (swz / ntn) << 8;
    const int tn0 = (swz % ntn) << 8;

    const int srl = lane >> 2;
    const int sch = (lane & 3) ^ (((lane >> 5) & 1) << 1);
    const int scol  = (wave & 1) * 32 + sch * 8;
    const int srow0 = (wave >> 1) * 16 + srl;

    const u16* pa[2][2];
    const u16* pb[2][2];
    pa[0][0] = A + (size_t)(tm0 + srow0)       * K + scol;
    pa[0][1] = A + (size_t)(tm0 + srow0 + 64)  * K + scol;
    pa[1][0] = A + (size_t)(tm0 + 128 + srow0)      * K + scol;
    pa[1][1] = A + (size_t)(tm0 + 128 + srow0 + 64) * K + scol;
    pb[0][0] = B + (size_t)(tn0 + srow0)       * K + scol;
    pb[0][1] = B + (size_t)(tn0 + srow0 + 64)  * K + scol;
    pb[1][0] = B + (size_t)(tn0 + 128 + srow0)      * K + scol;
    pb[1][1] = B + (size_t)(tn0 + 128 + srow0 + 64) * K + scol;

    auto STAGE = [&](int tau, int isB, int half) {
        if (tau < NT) {
            char* d = lds + (isB ? BOFF : 0) + (tau & 1) * 32768 + half * 16384 + wave * 1024;
            const u16* p0 = (isB ? pb[half][0] : pa[half][0]) + (size_t)tau * 64;
            const u16* p1 = (isB ? pb[half][1] : pa[half][1]) + (size_t)tau * 64;
            gld16(p0, d);
            gld16(p1, d + 8192);
        }
    };

    const int l15 = lane & 15, lhi = lane >> 4;
    const int pch = lhi ^ (((lane >> 3) & 1) << 1);
    const int lof = l15 * 64 + pch * 16;

    short8 a[4][2];
    short8 b[4][2];
    f32x4  acc[8][4] = {};

    const char* Ab;
    const char* Bb;
    auto LDA_ = [&](int mh) {
#pragma unroll
        for (int fm = 0; fm < 4; ++fm)
#pragma unroll
            for (int ks = 0; ks < 2; ++ks)
                a[fm][ks] = *(const short8*)(Ab + ((mh * 4 + fm) * 2 + ks) * 1024);
    };
    auto LDB_ = [&](int nh) {
#pragma unroll
        for (int fn = 0; fn < 2; ++fn)
#pragma unroll
            for (int ks = 0; ks < 2; ++ks)
                b[nh * 2 + fn][ks] = *(const short8*)(Bb + (((wn & 1) * 4 + nh * 2 + fn) * 2 + ks) * 1024);
    };
    auto MMA_ = [&](int mh, int nh) {
#pragma unroll
        for (int ks = 0; ks < 2; ++ks)
#pragma unroll
            for (int fm = 0; fm < 4; ++fm)
#pragma unroll
                for (int fn = 0; fn < 2; ++fn)
                    acc[mh * 4 + fm][nh * 2 + fn] = __builtin_amdgcn_mfma_f32_16x16x32_bf16(
                        a[fm][ks], b[nh * 2 + fn][ks], acc[mh * 4 + fm][nh * 2 + fn], 0, 0, 0);
    };

    STAGE(0, 0, 0); STAGE(0, 0, 1); STAGE(0, 1, 0); STAGE(0, 1, 1);
    STAGE(1, 1, 0); STAGE(1, 1, 1);
    asm volatile("s_waitcnt vmcnt(4)" ::: "memory");
    __builtin_amdgcn_s_barrier();

    for (int t = 0; t < NT; ++t) {
        Ab = lds + (t & 1) * 32768 + wm * 16384 + lof;
        Bb = lds + BOFF + (t & 1) * 32768 + (wn >> 1) * 16384 + lof;

        LDA_(0); LDB_(0);
        STAGE(t + 1, 0, 0);
        asm volatile("s_waitcnt lgkmcnt(8)" ::: "memory");
        SYNC_IN();
        __builtin_amdgcn_s_setprio(1);
        MMA_(0, 0);
        SYNC_OUT();

        LDB_(1);
        STAGE(t + 1, 0, 1);
        SYNC_IN();
        __builtin_amdgcn_s_setprio(1);
        MMA_(0, 1);
        SYNC_OUT();

        LDA_(1);
        STAGE(t + 2, 1, 0);
        SYNC_IN();
        __builtin_amdgcn_s_setprio(1);
        MMA_(1, 1);
        SYNC_OUT();

        STAGE(t + 2, 1, 1);
        __builtin_amdgcn_sched_barrier(0);
        __builtin_amdgcn_s_barrier();
        asm volatile("s_waitcnt lgkmcnt(0)" ::: "memory");
        __builtin_amdgcn_sched_barrier(0);
        __builtin_amdgcn_s_setprio(1);
        MMA_(1, 0);
        __builtin_amdgcn_s_setprio(0);
        __builtin_amdgcn_sched_barrier(0);
        if (t < NT - 2)       asm volatile("s_waitcnt vmcnt(4)" ::: "memory");
        else if (t == NT - 2) asm volatile("s_waitcnt vmcnt(0)" ::: "memory");
        __builtin_amdgcn_s_barrier();
    }

    const int orow = tm0 + wm * 128;
    const int ocol = tn0 + wn * 64;
    float bv[4];
#pragma unroll
    for (int fn = 0; fn < 4; ++fn) bv[fn] = bias[ocol + fn * 16 + l15];
#pragma unroll
    for (int fm = 0; fm < 8; ++fm) {
        const int row0 = orow + fm * 16 + lhi * 4;
#pragma unroll
        for (int fn = 0; fn < 4; ++fn) {
            const int col = ocol + fn * 16 + l15;
#pragma unroll
            for (int r = 0; r < 4; ++r) {
                float v = acc[fm][fn][r] + bv[fn];
                O[(size_t)(row0 + r) * N + col] = v > 0.f ? v : 0.f;
            }
        }
    }
}

// ---------------- launch ----------------

extern "C" void kernel_launch(void* const* d_in, const int* in_sizes, int n_in,
                              void* d_out, int out_size, void* d_ws, size_t ws_size,
                              hipStream_t stream) {
    const float* x    = (const float*)d_in[0];   // [8192, 8192]
    const float* W    = (const float*)d_in[1];   // [8192, 1024]
    const float* bias = (const float*)d_in[2];   // [8192]
    float* out = (float*)d_out;                  // [8192, 8192] fp32

    char* ws = (char*)d_ws;
    u16* xb = (u16*)ws;                                        // 134217728 B
    u16* wt = (u16*)(ws + 134217728);                          // [1024][8192]
    u16* wb = (u16*)(ws + 134217728 + 16777216);               // [8192][1024]
    u16* hb = (u16*)(ws + 134217728 + 2 * 16777216);           // [8192][1024]

    cvt_x_kernel<<<(BATCH * NFEAT / 8) / 256, 256, 0, stream>>>(x, xb);
    cvt_w_kernel<<<dim3(NFEAT / 64, DMODEL / 64), 256, 0, stream>>>(W, wb, wt);

    // h = x @ W -> bf16  (256x128 8-phase; grid 32*8 = 256 blocks = 1/CU)
    gemm1_8phase<<<dim3((BATCH / 256) * (DMODEL / 128)), 512, 0, stream>>>(
        xb, wt, hb, DMODEL, NFEAT);

    // out = relu(h @ W^T + bias)  (256^2 8-phase; 1024 blocks)
    gemm2_8phase<<<dim3((BATCH / 256) * (NFEAT / 256)), 512, 0, stream>>>(
        hb, wb, out, bias, NFEAT, DMODEL);
}